// Round 11
// baseline (171.921 us; speedup 1.0000x reference)
//
#include <hip/hip_runtime.h>
#include <hip/hip_bf16.h>

// Problem constants
#define B_   256
#define L_   197
#define C_   768
#define H_   48
#define NA_  10
#define ROWS (B_ * L_)            // 50432
#define NR16 (ROWS / 16)          // 3152 row-slabs
#define OFF_SIM 38731776          // B*L*C
#define OFF_IDX 38731777

typedef __attribute__((ext_vector_type(8))) short short8;
typedef __attribute__((ext_vector_type(4))) float f32x4;

static __device__ inline short f2bf(float f) {
    union { float f; unsigned u; } v; v.f = f;
    unsigned r = v.u + 0x7fffu + ((v.u >> 16) & 1u);   // round-to-nearest-even
    return (short)(r >> 16);
}

// ---------------------------------------------------------------------------
// Kw: convert ALL 10 adapters' W1 [10,48,768] and W2 [10,768,48] to bf16.
// W2 stored K-padded to 64 (zeros) so GEMM2 can use 16x16x32 mfma.
// ---------------------------------------------------------------------------
__global__ void kw_convert(const float* __restrict__ W1, const float* __restrict__ W2,
                           short* __restrict__ W1b, short* __restrict__ W2b) {
    int i = blockIdx.x * 256 + threadIdx.x;
    if (i < NA_ * H_ * C_)                     // 368640
        W1b[i] = f2bf(W1[i]);
    if (i < NA_ * C_ * 64) {                   // 491520
        int k  = i & 63;
        int nc = i >> 6;                       // a*768 + c
        W2b[i] = (k < H_) ? f2bf(W2[nc * H_ + k]) : (short)0;
    }
}

// ---------------------------------------------------------------------------
// K1a: partial sums over L. grid = B*4 blocks of 192 threads; thread t owns
// float4-column t. partial layout [b][seg][c] f32.
// ---------------------------------------------------------------------------
__global__ void k1a_partial(const float* __restrict__ x, float* __restrict__ partial) {
    int b = blockIdx.x >> 2, seg = blockIdx.x & 3;
    int l0 = seg * 50, l1 = l0 + 50; if (l1 > L_) l1 = L_;
    int t = threadIdx.x;                       // 0..191
    const float* xb = x + (size_t)b * L_ * C_ + t * 4;
    float4 s = {0.f, 0.f, 0.f, 0.f};
    #pragma unroll 5
    for (int l = l0; l < l1; ++l) {
        float4 v = *(const float4*)(xb + (size_t)l * C_);
        s.x += v.x; s.y += v.y; s.z += v.z; s.w += v.w;
    }
    *(float4*)(partial + ((size_t)b * 4 + seg) * C_ + t * 4) = s;
}

// ---------------------------------------------------------------------------
// K1b: per-b mean -> sims[b][k] (unchanged)
// ---------------------------------------------------------------------------
__global__ void k1b_sims(const float* __restrict__ partial, const float* __restrict__ akey,
                         float* __restrict__ sims) {
    __shared__ float red[21][256];
    int b = blockIdx.x, t = threadIdx.x;
    const float* p = partial + (size_t)b * 4 * C_;
    float m[3];
    #pragma unroll
    for (int j = 0; j < 3; ++j) {
        int c = t + j * 256;
        m[j] = (p[c] + p[C_ + c] + p[2 * C_ + c] + p[3 * C_ + c]) * (1.f / (float)L_);
    }
    red[0][t] = m[0] * m[0] + m[1] * m[1] + m[2] * m[2];
    #pragma unroll
    for (int k = 0; k < NA_; ++k) {
        float kd = 0.f, kq = 0.f;
        #pragma unroll
        for (int j = 0; j < 3; ++j) {
            float kv = akey[k * C_ + t + j * 256];
            kd += m[j] * kv; kq += kv * kv;
        }
        red[1 + k][t] = kd; red[11 + k][t] = kq;
    }
    __syncthreads();
    for (int s = 128; s > 0; s >>= 1) {
        if (t < s) {
            #pragma unroll
            for (int q = 0; q < 21; ++q) red[q][t] += red[q][t + s];
        }
        __syncthreads();
    }
    if (t < NA_) {
        float msq = red[0][0];
        sims[b * NA_ + t] = red[1 + t][0] * rsqrtf(fmaxf(red[11 + t][0], 1e-12f))
                                          * rsqrtf(fmaxf(msq, 1e-12f));
    }
}

// ---------------------------------------------------------------------------
// K2: single block. argmax + majority vote + reduce_sim + idx (unchanged)
// ---------------------------------------------------------------------------
__global__ void k2_select(const float* __restrict__ sims, float* __restrict__ out,
                          int* __restrict__ majorp) {
    __shared__ int counts[NA_];
    __shared__ int majorS;
    __shared__ float rs[256];
    int t = threadIdx.x;                       // = b
    float s[NA_];
    #pragma unroll
    for (int k = 0; k < NA_; ++k) s[k] = sims[t * NA_ + k];
    int best = 0; float bv = s[0];
    #pragma unroll
    for (int k = 1; k < NA_; ++k) { if (s[k] > bv) { bv = s[k]; best = k; } }
    if (t < NA_) counts[t] = 0;
    __syncthreads();
    atomicAdd(&counts[best], 1);
    __syncthreads();
    if (t == 0) {
        int mj = 0, mc = counts[0];
        #pragma unroll
        for (int k = 1; k < NA_; ++k) { if (counts[k] > mc) { mc = counts[k]; mj = k; } }
        majorS = mj; *majorp = mj;
    }
    __syncthreads();
    int mj = majorS;
    rs[t] = s[mj];
    __syncthreads();
    for (int st = 128; st > 0; st >>= 1) { if (t < st) rs[t] += rs[t + st]; __syncthreads(); }
    if (t == 0) out[OFF_SIM] = rs[0] * (1.f / (float)B_);
    out[OFF_IDX + t] = (float)mj;
}

// ---------------------------------------------------------------------------
// KA: GEMM1 with split-K=2. grid = (788, 2) x 256 threads (4 waves).
// Wave (r = bx*4+wid, s = by): 16 rows, K in [s*384, s*384+384).
// Writes f32 partials (NO relu) to hp[s][row][48].
// 6304 waves -> ~25/CU: latency hidden by TLP, not per-wave ILP.
// ---------------------------------------------------------------------------
__global__ void ka_gemm1(const float* __restrict__ x, const short* __restrict__ W1b,
                         const int* __restrict__ majorp, float* __restrict__ hp) {
    int wid = threadIdx.x >> 6, l = threadIdx.x & 63;
    int r = blockIdx.x * 4 + wid;              // 0..3151
    int s = blockIdx.y;                        // 0..1
    int lo16 = l & 15, g = l >> 4, klane = g * 8;
    const int major = *majorp;
    const short* w1r = W1b + major * (H_ * C_) + lo16 * C_ + s * 384 + klane;
    const float* xr  = x + (size_t)(16 * r + lo16) * C_ + s * 384 + klane;

    f32x4 a0 = {0,0,0,0}, a1 = {0,0,0,0}, a2 = {0,0,0,0};
    #pragma unroll 4
    for (int kk = 0; kk < 384; kk += 32) {
        float4 xa = *(const float4*)(xr + kk);
        float4 xb = *(const float4*)(xr + kk + 4);
        short8 w0 = *(const short8*)(w1r + kk);
        short8 w1f = *(const short8*)(w1r + 16 * C_ + kk);
        short8 w2f = *(const short8*)(w1r + 32 * C_ + kk);
        short8 af;
        af[0] = f2bf(xa.x); af[1] = f2bf(xa.y); af[2] = f2bf(xa.z); af[3] = f2bf(xa.w);
        af[4] = f2bf(xb.x); af[5] = f2bf(xb.y); af[6] = f2bf(xb.z); af[7] = f2bf(xb.w);
        a0 = __builtin_amdgcn_mfma_f32_16x16x32_bf16(af, w0,  a0, 0, 0, 0);
        a1 = __builtin_amdgcn_mfma_f32_16x16x32_bf16(af, w1f, a1, 0, 0, 0);
        a2 = __builtin_amdgcn_mfma_f32_16x16x32_bf16(af, w2f, a2, 0, 0, 0);
    }
    // D layout: lane l holds rows m=g*4+q, col n = ntile*16 + lo16
    float* hpr = hp + (size_t)s * ROWS * 48 + (size_t)(16 * r + g * 4) * 48 + lo16;
    #pragma unroll
    for (int q = 0; q < 4; ++q) {
        hpr[q * 48 +  0] = a0[q];
        hpr[q * 48 + 16] = a1[q];
        hpr[q * 48 + 32] = a2[q];
    }
}

// ---------------------------------------------------------------------------
// KB: GEMM2 + bias, column-panel split=6. grid = (788, 6) x 256 threads.
// Wave (r = bx*4+wid, p = by): 16 rows x 128 out-cols.
// h = relu(hp[0]+hp[1]) -> bf16 frags; swapped-operand mfma; out = x + relu(a).
// 18912 waves -> all 32 wave-slots/CU busy; x read exactly once across panels.
// ---------------------------------------------------------------------------
__global__ void kb_gemm2(const float* __restrict__ x, const short* __restrict__ W2b,
                         const int* __restrict__ majorp, const float* __restrict__ hp,
                         float* __restrict__ out) {
    int wid = threadIdx.x >> 6, l = threadIdx.x & 63;
    int r = blockIdx.x * 4 + wid;              // 0..3151
    int p = blockIdx.y;                        // 0..5
    int lo16 = l & 15, g = l >> 4, klane = g * 8;
    const int major = *majorp;
    const short* w2 = W2b + (size_t)major * (C_ * 64);

    int row = 16 * r + lo16;
    const float* h0 = hp + (size_t)row * 48;
    const float* h1 = hp + (size_t)ROWS * 48 + (size_t)row * 48;

    // hA: k = klane..klane+7 (<= 31 always valid)
    float4 s0a = *(const float4*)(h0 + klane);
    float4 s0b = *(const float4*)(h0 + klane + 4);
    float4 s1a = *(const float4*)(h1 + klane);
    float4 s1b = *(const float4*)(h1 + klane + 4);
    short8 hA;
    hA[0] = f2bf(fmaxf(s0a.x + s1a.x, 0.f)); hA[1] = f2bf(fmaxf(s0a.y + s1a.y, 0.f));
    hA[2] = f2bf(fmaxf(s0a.z + s1a.z, 0.f)); hA[3] = f2bf(fmaxf(s0a.w + s1a.w, 0.f));
    hA[4] = f2bf(fmaxf(s0b.x + s1b.x, 0.f)); hA[5] = f2bf(fmaxf(s0b.y + s1b.y, 0.f));
    hA[6] = f2bf(fmaxf(s0b.z + s1b.z, 0.f)); hA[7] = f2bf(fmaxf(s0b.w + s1b.w, 0.f));
    // hB: k = 32+klane..+7; valid only for g<2 (k<48), else zero (pad)
    short8 hB = {0,0,0,0,0,0,0,0};
    if (g < 2) {
        float4 t0a = *(const float4*)(h0 + 32 + klane);
        float4 t0b = *(const float4*)(h0 + 36 + klane);
        float4 t1a = *(const float4*)(h1 + 32 + klane);
        float4 t1b = *(const float4*)(h1 + 36 + klane);
        hB[0] = f2bf(fmaxf(t0a.x + t1a.x, 0.f)); hB[1] = f2bf(fmaxf(t0a.y + t1a.y, 0.f));
        hB[2] = f2bf(fmaxf(t0a.z + t1a.z, 0.f)); hB[3] = f2bf(fmaxf(t0a.w + t1a.w, 0.f));
        hB[4] = f2bf(fmaxf(t0b.x + t1b.x, 0.f)); hB[5] = f2bf(fmaxf(t0b.y + t1b.y, 0.f));
        hB[6] = f2bf(fmaxf(t0b.z + t1b.z, 0.f)); hB[7] = f2bf(fmaxf(t0b.w + t1b.w, 0.f));
    }

    // A = w2 frag (m = c-dim), B = h frag (n = row). D: lane l -> row n=lo16,
    // cols c = p*128 + i*16 + g*4 + {0..3}
    const short* w2r = w2 + (size_t)(p * 128 + lo16) * 64 + klane;
    const float* xr2 = x   + (size_t)row * C_ + p * 128 + g * 4;
    float*      outr = out + (size_t)row * C_ + p * 128 + g * 4;

    #pragma unroll
    for (int i = 0; i < 8; ++i) {
        f32x4 xv = *(const f32x4*)(xr2 + i * 16);
        short8 p0 = *(const short8*)(w2r + i * 16 * 64);
        short8 p1 = *(const short8*)(w2r + i * 16 * 64 + 32);
        f32x4 acc = {0,0,0,0};
        acc = __builtin_amdgcn_mfma_f32_16x16x32_bf16(p0, hA, acc, 0, 0, 0);
        acc = __builtin_amdgcn_mfma_f32_16x16x32_bf16(p1, hB, acc, 0, 0, 0);
        f32x4 ov;
        ov[0] = xv[0] + fmaxf(acc[0], 0.f);
        ov[1] = xv[1] + fmaxf(acc[1], 0.f);
        ov[2] = xv[2] + fmaxf(acc[2], 0.f);
        ov[3] = xv[3] + fmaxf(acc[3], 0.f);
        *(f32x4*)(outr + i * 16) = ov;
    }
}

// ---------------------------------------------------------------------------
extern "C" void kernel_launch(void* const* d_in, const int* in_sizes, int n_in,
                              void* d_out, int out_size, void* d_ws, size_t ws_size,
                              hipStream_t stream) {
    const float* x    = (const float*)d_in[0];
    const float* W1   = (const float*)d_in[1];
    const float* W2   = (const float*)d_in[2];
    const float* akey = (const float*)d_in[3];
    float* out = (float*)d_out;

    char* ws = (char*)d_ws;
    short* W1b     = (short*)ws;                       //   737,280 B
    short* W2b     = (short*)(ws + 737280);            //   983,040 B
    float* partial = (float*)(ws + 1720320);           // 3,145,728 B
    float* sims    = (float*)(ws + 4866048);           //    10,240 B
    int*   majorp  = (int*)(ws + 4876288);             //         4 B
    float* hp      = (float*)(ws + 4876544);           // 19,365,888 B (2 x ROWS x 48 f32)

    hipLaunchKernelGGL(kw_convert, dim3(1920), dim3(256), 0, stream, W1, W2, W1b, W2b);
    hipLaunchKernelGGL(k1a_partial, dim3(B_ * 4), dim3(192), 0, stream, x, partial);
    hipLaunchKernelGGL(k1b_sims, dim3(B_), dim3(256), 0, stream, partial, akey, sims);
    hipLaunchKernelGGL(k2_select, dim3(1), dim3(256), 0, stream, sims, out, majorp);
    hipLaunchKernelGGL(ka_gemm1, dim3(NR16 / 4, 2), dim3(256), 0, stream, x, W1b, majorp, hp);
    hipLaunchKernelGGL(kb_gemm2, dim3(NR16 / 4, 6), dim3(256), 0, stream, x, W2b, majorp, hp, out);
}

// Round 12
// 158.585 us; speedup vs baseline: 1.0841x; 1.0841x over previous
//
#include <hip/hip_runtime.h>
#include <hip/hip_bf16.h>

// Problem constants
#define B_   256
#define L_   197
#define C_   768
#define H_   48
#define NA_  10
#define ROWS (B_ * L_)            // 50432
#define OFF_SIM 38731776          // B*L*C
#define OFF_IDX 38731777

typedef __attribute__((ext_vector_type(8))) short short8;
typedef __attribute__((ext_vector_type(4))) short short4_t;
typedef __attribute__((ext_vector_type(4))) float f32x4;

static __device__ inline short f2bf(float f) {
    union { float f; unsigned u; } v; v.f = f;
    unsigned r = v.u + 0x7fffu + ((v.u >> 16) & 1u);   // round-to-nearest-even
    return (short)(r >> 16);
}

#define GLOAD(dst, p)          asm volatile("global_load_dwordx4 %0, %1, off"            : "=v"(dst) : "v"(p))
#define GLOADO(dst, p, OFFSTR) asm volatile("global_load_dwordx4 %0, %1, off offset:" OFFSTR : "=v"(dst) : "v"(p))

// ---------------------------------------------------------------------------
// Kw: convert ALL 10 adapters' W1 [10,48,768] and W2 [10,768,48] to bf16.
// W2 stored K-padded to 64 (zeros) so GEMM2 can use 16x16x32 mfma.
// ---------------------------------------------------------------------------
__global__ void kw_convert(const float* __restrict__ W1, const float* __restrict__ W2,
                           short* __restrict__ W1b, short* __restrict__ W2b) {
    int i = blockIdx.x * 256 + threadIdx.x;
    if (i < NA_ * H_ * C_)                     // 368640
        W1b[i] = f2bf(W1[i]);
    if (i < NA_ * C_ * 64) {                   // 491520
        int k  = i & 63;
        int nc = i >> 6;                       // a*768 + c
        W2b[i] = (k < H_) ? f2bf(W2[nc * H_ + k]) : (short)0;
    }
}

// ---------------------------------------------------------------------------
// K1a: partial sums over L. grid = B*4 blocks of 192 threads; thread t owns
// float4-column t. partial layout [b][seg][c] f32.
// ---------------------------------------------------------------------------
__global__ void k1a_partial(const float* __restrict__ x, float* __restrict__ partial) {
    int b = blockIdx.x >> 2, seg = blockIdx.x & 3;
    int l0 = seg * 50, l1 = l0 + 50; if (l1 > L_) l1 = L_;
    int t = threadIdx.x;                       // 0..191
    const float* xb = x + (size_t)b * L_ * C_ + t * 4;
    float4 s = {0.f, 0.f, 0.f, 0.f};
    #pragma unroll 5
    for (int l = l0; l < l1; ++l) {
        float4 v = *(const float4*)(xb + (size_t)l * C_);
        s.x += v.x; s.y += v.y; s.z += v.z; s.w += v.w;
    }
    *(float4*)(partial + ((size_t)b * 4 + seg) * C_ + t * 4) = s;
}

// ---------------------------------------------------------------------------
// K1b: per-b mean -> sims[b][k] (unchanged)
// ---------------------------------------------------------------------------
__global__ void k1b_sims(const float* __restrict__ partial, const float* __restrict__ akey,
                         float* __restrict__ sims) {
    __shared__ float red[21][256];
    int b = blockIdx.x, t = threadIdx.x;
    const float* p = partial + (size_t)b * 4 * C_;
    float m[3];
    #pragma unroll
    for (int j = 0; j < 3; ++j) {
        int c = t + j * 256;
        m[j] = (p[c] + p[C_ + c] + p[2 * C_ + c] + p[3 * C_ + c]) * (1.f / (float)L_);
    }
    red[0][t] = m[0] * m[0] + m[1] * m[1] + m[2] * m[2];
    #pragma unroll
    for (int k = 0; k < NA_; ++k) {
        float kd = 0.f, kq = 0.f;
        #pragma unroll
        for (int j = 0; j < 3; ++j) {
            float kv = akey[k * C_ + t + j * 256];
            kd += m[j] * kv; kq += kv * kv;
        }
        red[1 + k][t] = kd; red[11 + k][t] = kq;
    }
    __syncthreads();
    for (int s = 128; s > 0; s >>= 1) {
        if (t < s) {
            #pragma unroll
            for (int q = 0; q < 21; ++q) red[q][t] += red[q][t + s];
        }
        __syncthreads();
    }
    if (t < NA_) {
        float msq = red[0][0];
        sims[b * NA_ + t] = red[1 + t][0] * rsqrtf(fmaxf(red[11 + t][0], 1e-12f))
                                          * rsqrtf(fmaxf(msq, 1e-12f));
    }
}

// ---------------------------------------------------------------------------
// K2: single block. argmax + majority vote + reduce_sim + idx (unchanged)
// ---------------------------------------------------------------------------
__global__ void k2_select(const float* __restrict__ sims, float* __restrict__ out,
                          int* __restrict__ majorp) {
    __shared__ int counts[NA_];
    __shared__ int majorS;
    __shared__ float rs[256];
    int t = threadIdx.x;                       // = b
    float s[NA_];
    #pragma unroll
    for (int k = 0; k < NA_; ++k) s[k] = sims[t * NA_ + k];
    int best = 0; float bv = s[0];
    #pragma unroll
    for (int k = 1; k < NA_; ++k) { if (s[k] > bv) { bv = s[k]; best = k; } }
    if (t < NA_) counts[t] = 0;
    __syncthreads();
    atomicAdd(&counts[best], 1);
    __syncthreads();
    if (t == 0) {
        int mj = 0, mc = counts[0];
        #pragma unroll
        for (int k = 1; k < NA_; ++k) { if (counts[k] > mc) { mc = counts[k]; mj = k; } }
        majorS = mj; *majorp = mj;
    }
    __syncthreads();
    int mj = majorS;
    rs[t] = s[mj];
    __syncthreads();
    for (int st = 128; st > 0; st >>= 1) { if (t < st) rs[t] += rs[t + st]; __syncthreads(); }
    if (t == 0) out[OFF_SIM] = rs[0] * (1.f / (float)B_);
    out[OFF_IDX + t] = (float)mj;
}

// ---------------------------------------------------------------------------
// K3: fused adapter apply. grid = ROWS/32 blocks, 128 threads (2 waves).
// Inline-asm forced load bursts (T14 async-stage): asm volatile
// global_load_dwordx4 issue (order pinned, dests live), one
// s_waitcnt vmcnt(0) asm with "+v" ties on every value (consumers
// data-depend on it), sched_barrier(0). Compiler cannot sink/serialize.
// Phase 1 = 6 bursts x 4 k-iters (20 loads); phase 2 = 8 bursts x 6 c-iters
// (18 loads), swapped-operand mfma, f32x4 stores.
// ---------------------------------------------------------------------------
__global__ void k3_apply(const float* __restrict__ x, const short* __restrict__ W1b,
                         const short* __restrict__ W2b, const int* __restrict__ majorp,
                         float* __restrict__ out) {
    __shared__ short hb[32 * 72];
    const int major = *majorp;
    const short* w1 = W1b + major * (H_ * C_);
    const short* w2 = W2b + (size_t)major * (C_ * 64);

    int t = threadIdx.x;
    int w = t >> 6, l = t & 63;
    int rbase = blockIdx.x * 32 + w * 16;
    int lo16 = l & 15;
    int klane = (l >> 4) * 8;

    // zero the K-pad region [48,64) of this wave's 16 hb rows
    {
        int row = w * 16 + lo16;
        short4_t z = {0, 0, 0, 0};
        *(short4_t*)&hb[row * 72 + 48 + (l >> 4) * 4] = z;
    }

    // ---- phase 1: h[16][48] = relu(x_tile @ W1^T), 6 forced bursts ----
    const float* xr  = x + (size_t)(rbase + lo16) * C_ + klane;
    const short* w1r = w1 + lo16 * C_ + klane;

    f32x4 acc0 = {0,0,0,0}, acc1 = {0,0,0,0}, acc2 = {0,0,0,0};

    #pragma unroll
    for (int j = 0; j < 6; ++j) {
        const float* px  = xr + j * 128;              // 4 iters x 32 floats
        const short* pw0 = w1r + j * 128;
        const short* pw1 = w1r + 16 * C_ + j * 128;
        const short* pw2 = w1r + 32 * C_ + j * 128;
        f32x4 xa0, xb0, xa1, xb1, xa2, xb2, xa3, xb3;
        short8 wa0, wb0, wc0, wa1, wb1, wc1, wa2, wb2, wc2, wa3, wb3, wc3;
        GLOAD (xa0, px);
        GLOADO(xb0, px, "16");
        GLOADO(xa1, px, "128");
        GLOADO(xb1, px, "144");
        GLOADO(xa2, px, "256");
        GLOADO(xb2, px, "272");
        GLOADO(xa3, px, "384");
        GLOADO(xb3, px, "400");
        GLOAD (wa0, pw0);
        GLOADO(wa1, pw0, "64");
        GLOADO(wa2, pw0, "128");
        GLOADO(wa3, pw0, "192");
        GLOAD (wb0, pw1);
        GLOADO(wb1, pw1, "64");
        GLOADO(wb2, pw1, "128");
        GLOADO(wb3, pw1, "192");
        GLOAD (wc0, pw2);
        GLOADO(wc1, pw2, "64");
        GLOADO(wc2, pw2, "128");
        GLOADO(wc3, pw2, "192");
        asm volatile("s_waitcnt vmcnt(0)"
            : "+v"(xa0), "+v"(xb0), "+v"(xa1), "+v"(xb1),
              "+v"(xa2), "+v"(xb2), "+v"(xa3), "+v"(xb3),
              "+v"(wa0), "+v"(wb0), "+v"(wc0), "+v"(wa1), "+v"(wb1), "+v"(wc1),
              "+v"(wa2), "+v"(wb2), "+v"(wc2), "+v"(wa3), "+v"(wb3), "+v"(wc3));
        __builtin_amdgcn_sched_barrier(0);
        // --- consume: 4 iterations ---
        short8 af;
        af[0] = f2bf(xa0[0]); af[1] = f2bf(xa0[1]); af[2] = f2bf(xa0[2]); af[3] = f2bf(xa0[3]);
        af[4] = f2bf(xb0[0]); af[5] = f2bf(xb0[1]); af[6] = f2bf(xb0[2]); af[7] = f2bf(xb0[3]);
        acc0 = __builtin_amdgcn_mfma_f32_16x16x32_bf16(af, wa0, acc0, 0, 0, 0);
        acc1 = __builtin_amdgcn_mfma_f32_16x16x32_bf16(af, wb0, acc1, 0, 0, 0);
        acc2 = __builtin_amdgcn_mfma_f32_16x16x32_bf16(af, wc0, acc2, 0, 0, 0);
        af[0] = f2bf(xa1[0]); af[1] = f2bf(xa1[1]); af[2] = f2bf(xa1[2]); af[3] = f2bf(xa1[3]);
        af[4] = f2bf(xb1[0]); af[5] = f2bf(xb1[1]); af[6] = f2bf(xb1[2]); af[7] = f2bf(xb1[3]);
        acc0 = __builtin_amdgcn_mfma_f32_16x16x32_bf16(af, wa1, acc0, 0, 0, 0);
        acc1 = __builtin_amdgcn_mfma_f32_16x16x32_bf16(af, wb1, acc1, 0, 0, 0);
        acc2 = __builtin_amdgcn_mfma_f32_16x16x32_bf16(af, wc1, acc2, 0, 0, 0);
        af[0] = f2bf(xa2[0]); af[1] = f2bf(xa2[1]); af[2] = f2bf(xa2[2]); af[3] = f2bf(xa2[3]);
        af[4] = f2bf(xb2[0]); af[5] = f2bf(xb2[1]); af[6] = f2bf(xb2[2]); af[7] = f2bf(xb2[3]);
        acc0 = __builtin_amdgcn_mfma_f32_16x16x32_bf16(af, wa2, acc0, 0, 0, 0);
        acc1 = __builtin_amdgcn_mfma_f32_16x16x32_bf16(af, wb2, acc1, 0, 0, 0);
        acc2 = __builtin_amdgcn_mfma_f32_16x16x32_bf16(af, wc2, acc2, 0, 0, 0);
        af[0] = f2bf(xa3[0]); af[1] = f2bf(xa3[1]); af[2] = f2bf(xa3[2]); af[3] = f2bf(xa3[3]);
        af[4] = f2bf(xb3[0]); af[5] = f2bf(xb3[1]); af[6] = f2bf(xb3[2]); af[7] = f2bf(xb3[3]);
        acc0 = __builtin_amdgcn_mfma_f32_16x16x32_bf16(af, wa3, acc0, 0, 0, 0);
        acc1 = __builtin_amdgcn_mfma_f32_16x16x32_bf16(af, wb3, acc1, 0, 0, 0);
        acc2 = __builtin_amdgcn_mfma_f32_16x16x32_bf16(af, wc3, acc2, 0, 0, 0);
    }

    // store h tile to LDS (D layout: col = lane&15, row = (lane>>4)*4 + r)
    {
        int hrow0 = w * 16 + (l >> 4) * 4;
        #pragma unroll
        for (int r = 0; r < 4; ++r) {
            hb[(hrow0 + r) * 72 +  0 + lo16] = f2bf(fmaxf(acc0[r], 0.f));
            hb[(hrow0 + r) * 72 + 16 + lo16] = f2bf(fmaxf(acc1[r], 0.f));
            hb[(hrow0 + r) * 72 + 32 + lo16] = f2bf(fmaxf(acc2[r], 0.f));
        }
    }
    __syncthreads();

    // ---- phase 2: a = relu(h @ W2^T), 8 forced bursts of 6 c-iters ----
    // A = w2 frag, B = h frag; D: lane holds 4 consecutive c of one x-row.
    short8 hA = *(const short8*)&hb[(w * 16 + lo16) * 72 + klane];
    short8 hB = *(const short8*)&hb[(w * 16 + lo16) * 72 + 32 + klane];
    const short* w2r = w2 + (size_t)lo16 * 64 + klane;
    const float* xr2 = x   + (size_t)(rbase + lo16) * C_ + (l >> 4) * 4;
    float*      outr = out + (size_t)(rbase + lo16) * C_ + (l >> 4) * 4;

    #pragma unroll
    for (int j = 0; j < 8; ++j) {
        const int i0 = j * 6;
        const float* px = xr2 + i0 * 16;              // iter stride 16 floats = 64B
        const short* pa = w2r + (size_t)i0 * 1024;    // iter stride 1024 shorts = 2048B
        const short* pb = w2r + (size_t)(i0 + 2) * 1024;
        const short* pc = w2r + (size_t)(i0 + 4) * 1024;
        f32x4 xv0, xv1, xv2, xv3, xv4, xv5;
        short8 p00, p10, p01, p11, p02, p12, p03, p13, p04, p14, p05, p15;
        GLOAD (xv0, px);
        GLOADO(xv1, px, "64");
        GLOADO(xv2, px, "128");
        GLOADO(xv3, px, "192");
        GLOADO(xv4, px, "256");
        GLOADO(xv5, px, "320");
        GLOAD (p00, pa);
        GLOADO(p10, pa, "64");
        GLOADO(p01, pa, "2048");
        GLOADO(p11, pa, "2112");
        GLOAD (p02, pb);
        GLOADO(p12, pb, "64");
        GLOADO(p03, pb, "2048");
        GLOADO(p13, pb, "2112");
        GLOAD (p04, pc);
        GLOADO(p14, pc, "64");
        GLOADO(p05, pc, "2048");
        GLOADO(p15, pc, "2112");
        asm volatile("s_waitcnt vmcnt(0)"
            : "+v"(xv0), "+v"(xv1), "+v"(xv2), "+v"(xv3), "+v"(xv4), "+v"(xv5),
              "+v"(p00), "+v"(p10), "+v"(p01), "+v"(p11), "+v"(p02), "+v"(p12),
              "+v"(p03), "+v"(p13), "+v"(p04), "+v"(p14), "+v"(p05), "+v"(p15));
        __builtin_amdgcn_sched_barrier(0);
        // --- consume: 6 iterations ---
        f32x4 acc, ov;
        acc = (f32x4){0,0,0,0};
        acc = __builtin_amdgcn_mfma_f32_16x16x32_bf16(p00, hA, acc, 0, 0, 0);
        acc = __builtin_amdgcn_mfma_f32_16x16x32_bf16(p10, hB, acc, 0, 0, 0);
        ov[0] = xv0[0] + fmaxf(acc[0], 0.f); ov[1] = xv0[1] + fmaxf(acc[1], 0.f);
        ov[2] = xv0[2] + fmaxf(acc[2], 0.f); ov[3] = xv0[3] + fmaxf(acc[3], 0.f);
        *(f32x4*)(outr + (i0 + 0) * 16) = ov;
        acc = (f32x4){0,0,0,0};
        acc = __builtin_amdgcn_mfma_f32_16x16x32_bf16(p01, hA, acc, 0, 0, 0);
        acc = __builtin_amdgcn_mfma_f32_16x16x32_bf16(p11, hB, acc, 0, 0, 0);
        ov[0] = xv1[0] + fmaxf(acc[0], 0.f); ov[1] = xv1[1] + fmaxf(acc[1], 0.f);
        ov[2] = xv1[2] + fmaxf(acc[2], 0.f); ov[3] = xv1[3] + fmaxf(acc[3], 0.f);
        *(f32x4*)(outr + (i0 + 1) * 16) = ov;
        acc = (f32x4){0,0,0,0};
        acc = __builtin_amdgcn_mfma_f32_16x16x32_bf16(p02, hA, acc, 0, 0, 0);
        acc = __builtin_amdgcn_mfma_f32_16x16x32_bf16(p12, hB, acc, 0, 0, 0);
        ov[0] = xv2[0] + fmaxf(acc[0], 0.f); ov[1] = xv2[1] + fmaxf(acc[1], 0.f);
        ov[2] = xv2[2] + fmaxf(acc[2], 0.f); ov[3] = xv2[3] + fmaxf(acc[3], 0.f);
        *(f32x4*)(outr + (i0 + 2) * 16) = ov;
        acc = (f32x4){0,0,0,0};
        acc = __builtin_amdgcn_mfma_f32_16x16x32_bf16(p03, hA, acc, 0, 0, 0);
        acc = __builtin_amdgcn_mfma_f32_16x16x32_bf16(p13, hB, acc, 0, 0, 0);
        ov[0] = xv3[0] + fmaxf(acc[0], 0.f); ov[1] = xv3[1] + fmaxf(acc[1], 0.f);
        ov[2] = xv3[2] + fmaxf(acc[2], 0.f); ov[3] = xv3[3] + fmaxf(acc[3], 0.f);
        *(f32x4*)(outr + (i0 + 3) * 16) = ov;
        acc = (f32x4){0,0,0,0};
        acc = __builtin_amdgcn_mfma_f32_16x16x32_bf16(p04, hA, acc, 0, 0, 0);
        acc = __builtin_amdgcn_mfma_f32_16x16x32_bf16(p14, hB, acc, 0, 0, 0);
        ov[0] = xv4[0] + fmaxf(acc[0], 0.f); ov[1] = xv4[1] + fmaxf(acc[1], 0.f);
        ov[2] = xv4[2] + fmaxf(acc[2], 0.f); ov[3] = xv4[3] + fmaxf(acc[3], 0.f);
        *(f32x4*)(outr + (i0 + 4) * 16) = ov;
        acc = (f32x4){0,0,0,0};
        acc = __builtin_amdgcn_mfma_f32_16x16x32_bf16(p05, hA, acc, 0, 0, 0);
        acc = __builtin_amdgcn_mfma_f32_16x16x32_bf16(p15, hB, acc, 0, 0, 0);
        ov[0] = xv5[0] + fmaxf(acc[0], 0.f); ov[1] = xv5[1] + fmaxf(acc[1], 0.f);
        ov[2] = xv5[2] + fmaxf(acc[2], 0.f); ov[3] = xv5[3] + fmaxf(acc[3], 0.f);
        *(f32x4*)(outr + (i0 + 5) * 16) = ov;
    }
}

// ---------------------------------------------------------------------------
extern "C" void kernel_launch(void* const* d_in, const int* in_sizes, int n_in,
                              void* d_out, int out_size, void* d_ws, size_t ws_size,
                              hipStream_t stream) {
    const float* x    = (const float*)d_in[0];
    const float* W1   = (const float*)d_in[1];
    const float* W2   = (const float*)d_in[2];
    const float* akey = (const float*)d_in[3];
    float* out = (float*)d_out;

    char* ws = (char*)d_ws;
    short* W1b     = (short*)ws;                       //   737,280 B
    short* W2b     = (short*)(ws + 737280);            //   983,040 B
    float* partial = (float*)(ws + 1720320);           // 3,145,728 B
    float* sims    = (float*)(ws + 4866048);           //    10,240 B
    int*   majorp  = (int*)(ws + 4876288);

    hipLaunchKernelGGL(kw_convert, dim3(1920), dim3(256), 0, stream, W1, W2, W1b, W2b);
    hipLaunchKernelGGL(k1a_partial, dim3(B_ * 4), dim3(192), 0, stream, x, partial);
    hipLaunchKernelGGL(k1b_sims, dim3(B_), dim3(256), 0, stream, partial, akey, sims);
    hipLaunchKernelGGL(k2_select, dim3(1), dim3(256), 0, stream, sims, out, majorp);
    hipLaunchKernelGGL(k3_apply, dim3(ROWS / 32), dim3(128), 0, stream, x, W1b, W2b, majorp, out);
}